// Round 9
// baseline (292.513 us; speedup 1.0000x reference)
//
#include <hip/hip_runtime.h>

// Problem constants (from reference): F=50000, K=32, E=128, N=100000
#define F_TOTAL 50000
#define N_NODE  100000
#define KNBR    32
#define EMB     128
#define FB      16      // f-rows per block (3125 * 16 == 50000 exactly)
#define RPW     4       // rows per wave (4 waves * 4 = 16)

// ---------------------------------------------------------------------------
// Kernel 1: y[n] = embi[n] . u   (rank-1 score is f-independent)
// 8 rows per wave: 8 independent 512B loads, multi-value butterfly
// (bits 4,2,1) + xor 8/16/32 folds. 3125*4*8 = 100000 exactly.
// ---------------------------------------------------------------------------
__global__ __launch_bounds__(256)
void node_scores(const float* __restrict__ embi,
                 const float* __restrict__ u,
                 float*       __restrict__ y)
{
    const int wave = threadIdx.x >> 6;
    const int lane = threadIdx.x & 63;
    const float2 uv = *(const float2*)(u + 2 * lane);

    const int base = (blockIdx.x * 4 + wave) * 8;

    float v[8];
#pragma unroll
    for (int j = 0; j < 8; ++j) {
        const float2 e = *(const float2*)(embi + (size_t)(base + j) * EMB + 2 * lane);
        v[j] = e.x * uv.x + e.y * uv.y;
    }

#pragma unroll
    for (int bit = 4; bit >= 1; bit >>= 1) {
        const bool upper = (lane & bit) != 0;
#pragma unroll
        for (int j = 0; j < bit; ++j) {
            const float send = upper ? v[j] : v[j + bit];
            const float recv = __shfl_xor(send, bit);
            v[j] = (upper ? v[j + bit] : v[j]) + recv;
        }
    }
    float d = v[0];
    d += __shfl_xor(d, 8);
    d += __shfl_xor(d, 16);
    d += __shfl_xor(d, 32);   // full 64-lane sum for row base + (lane&7)

    if (lane < 8) y[base + lane] = d;
}

// ---------------------------------------------------------------------------
// Kernel 2: attention aggregate, LDS-FREE for max occupancy.
// r5/r7 lesson: per-wave load depth is compiler-pinned at ~8; so scale
// CONCURRENCY via waves instead. No LDS, VGPR ~52 -> thread-capped at
// 8 blocks/CU = 32 waves/CU (was 3 blocks = 12 waves with the fused 24KB).
// Writes agg into d_out (consumed+overwritten in place by kernel 3).
// ---------------------------------------------------------------------------
__global__ __launch_bounds__(256)
void attn_agg(const int*   __restrict__ adj,    // [F,K] int32
              const float* __restrict__ embi,   // [N,E]
              const float* __restrict__ y,      // [N] precomputed scores
              float*       __restrict__ agg)    // [F,E] == d_out
{
    const int wave  = threadIdx.x >> 6;
    const int lane  = threadIdx.x & 63;
    const int fbase = blockIdx.x * FB;

    for (int i = 0; i < RPW; ++i) {
        const int r = wave * RPW + i;
        const int f = fbase + r;

        const int myidx = adj[f * KNBR + (lane & 31)];

        // score gather (y is 400KB, L2-resident) + pad mask (index 0 = pad)
        float alpha = y[myidx] + ((myidx != 0) ? 0.0f : -10000.0f);

        // softmax over the 32 k's (half-waves hold identical data)
        float mx = alpha;
#pragma unroll
        for (int bit = 1; bit <= 16; bit <<= 1)
            mx = fmaxf(mx, __shfl_xor(mx, bit));
        const float e = __expf(alpha - mx);
        float s = e;
#pragma unroll
        for (int bit = 1; bit <= 16; bit <<= 1)
            s += __shfl_xor(s, bit);
        const float an = e / s;   // normalized weight for k = lane&31

        // aggregate: chunks of 8 rows (compiler keeps ~8 loads in flight;
        // cross-wave TLP supplies the rest of the latency hiding)
        float2 acc = make_float2(0.f, 0.f);
#pragma unroll
        for (int c = 0; c < KNBR / 8; ++c) {
            float2 nb[8];
#pragma unroll
            for (int j = 0; j < 8; ++j) {
                const unsigned ik =
                    (unsigned)__builtin_amdgcn_readlane(myidx, c * 8 + j);
                nb[j] = *(const float2*)(embi + (size_t)ik * EMB + 2 * lane);
            }
#pragma unroll
            for (int j = 0; j < 8; ++j) {
                const float a = __uint_as_float((unsigned)__builtin_amdgcn_readlane(
                    (int)__float_as_uint(an), c * 8 + j));
                acc.x = fmaf(a, nb[j].x, acc.x);
                acc.y = fmaf(a, nb[j].y, acc.y);
            }
        }

        *(float2*)(agg + (size_t)f * EMB + 2 * lane) = acc;
    }
}

// ---------------------------------------------------------------------------
// Kernel 3: gated fusion. Stages embf + agg (= out, read in place) into LDS,
// then the proven gate GEMM: thread -> column pair, wave -> j-quarter,
// W (128KB) read once per block (L2-hot), LDS partial combine, in-place
// overwrite of this block's 16 rows. Block-local RAW only.
// ---------------------------------------------------------------------------
__global__ __launch_bounds__(256)
void gate_fuse(const float* __restrict__ embf,   // [F,E]
               const float* __restrict__ W,      // [E,2E]
               const float* __restrict__ bias,   // [E]
               float*       __restrict__ out)    // [F,E]: in = agg, out = result
{
    __shared__ float catbuf[FB][2 * EMB];  // 16 KB: [r][0:128)=embf, [128:256)=agg
    __shared__ float pbuf[FB][EMB];        //  8 KB

    const int tid   = threadIdx.x;
    const int fbase = blockIdx.x * FB;

    // stage: 16 rows x 128 cols of embf and agg; 512 float4 each, 2/thread
#pragma unroll
    for (int q = 0; q < 2; ++q) {
        const int idx = q * 256 + tid;     // 0..511
        const int r   = idx >> 5;          // 32 float4 per row
        const int c   = (idx & 31) * 4;
        *(float4*)&catbuf[r][c] =
            *(const float4*)(embf + (size_t)(fbase + r) * EMB + c);
        *(float4*)&catbuf[r][EMB + c] =
            *(const float4*)(out + (size_t)(fbase + r) * EMB + c);
    }
    __syncthreads();

    // gate GEMM: thread -> (column pair c0,c1 ; j-quarter g)
    const int p  = tid & 63;
    const int g  = tid >> 6;       // wave index (divergence is wave-uniform)
    const int c0 = 2 * p, c1 = c0 + 1;
    const int jbase = g * 64;

    float acc0[FB], acc1[FB];
#pragma unroll
    for (int r = 0; r < FB; ++r) { acc0[r] = 0.f; acc1[r] = 0.f; }

    const float* W0 = W + (size_t)c0 * (2 * EMB) + jbase;
    const float* W1 = W + (size_t)c1 * (2 * EMB) + jbase;

#pragma unroll 4
    for (int j = 0; j < 64; j += 4) {
        const float4 w0 = *(const float4*)(W0 + j);
        const float4 w1 = *(const float4*)(W1 + j);
#pragma unroll
        for (int r = 0; r < FB; ++r) {
            const float4 cv = *(const float4*)&catbuf[r][jbase + j];  // broadcast
            acc0[r] += cv.x * w0.x + cv.y * w0.y + cv.z * w0.z + cv.w * w0.w;
            acc1[r] += cv.x * w1.x + cv.y * w1.y + cv.z * w1.z + cv.w * w1.w;
        }
    }

    // combine the 4 j-quarter partials via LDS (wave-serialized, cheap)
    if (g == 3) {
#pragma unroll
        for (int r = 0; r < FB; ++r) { pbuf[r][c0] = acc0[r]; pbuf[r][c1] = acc1[r]; }
    }
    __syncthreads();
    if (g == 2) {
#pragma unroll
        for (int r = 0; r < FB; ++r) { pbuf[r][c0] += acc0[r]; pbuf[r][c1] += acc1[r]; }
    }
    __syncthreads();
    if (g == 1) {
#pragma unroll
        for (int r = 0; r < FB; ++r) { pbuf[r][c0] += acc0[r]; pbuf[r][c1] += acc1[r]; }
    }
    __syncthreads();
    if (g == 0) {
        const float2 bv = *(const float2*)(bias + c0);
#pragma unroll
        for (int r = 0; r < FB; ++r) {
            const float t0 = acc0[r] + pbuf[r][c0] + bv.x;
            const float t1 = acc1[r] + pbuf[r][c1] + bv.y;
            const float g0 = 1.f / (1.f + __expf(-t0));
            const float g1 = 1.f / (1.f + __expf(-t1));
            const float e0 = catbuf[r][c0],       e1 = catbuf[r][c1];
            const float a0 = catbuf[r][EMB + c0], a1 = catbuf[r][EMB + c1];
            float2 o;
            o.x = g0 * e0 + (1.f - g0) * a0;
            o.y = g1 * e1 + (1.f - g1) * a1;
            *(float2*)(out + (size_t)(fbase + r) * EMB + c0) = o;
        }
    }
}

extern "C" void kernel_launch(void* const* d_in, const int* in_sizes, int n_in,
                              void* d_out, int out_size, void* d_ws, size_t ws_size,
                              hipStream_t stream) {
    const int*   adj  = (const int*)  d_in[0];  // adjacency_fi [F,K] int32
    const float* embi = (const float*)d_in[1];  // embedding_i [N,E]
    const float* embf = (const float*)d_in[2];  // embedding_f_weight [F,E]
    const float* u    = (const float*)d_in[3];  // u [E,1]
    const float* W    = (const float*)d_in[4];  // W_weight [E,2E]
    const float* bias = (const float*)d_in[5];  // W_bias [E]
    float* outp = (float*)d_out;
    float* y    = (float*)d_ws;                 // N_NODE floats (400 KB scratch)

    node_scores<<<3125, 256, 0, stream>>>(embi, u, y);
    attn_agg  <<<F_TOTAL / FB, 256, 0, stream>>>(adj, embi, y, outp);
    gate_fuse <<<F_TOTAL / FB, 256, 0, stream>>>(embf, W, bias, outp);
}